// Round 9
// baseline (123.173 us; speedup 1.0000x reference)
//
#include <hip/hip_runtime.h>

// CrossModalAttention  B=8, CQ=CKV=E=256, Nq=4096, Nkv=1024
// out = concat([C, (out_w@g_w@P) @ softmax(thetaC^T @ phiP / 16)^T], axis=1)

typedef __attribute__((ext_vector_type(8))) short short8;   // 8 bf16 raw
typedef __attribute__((ext_vector_type(16))) float f32x16;
typedef unsigned short ushort_t;

__device__ __forceinline__ unsigned short f2bf(float f) {
    unsigned int u = __float_as_uint(f);
    u += 0x7FFFu + ((u >> 16) & 1u);            // RNE
    return (unsigned short)(u >> 16);
}
__device__ __forceinline__ unsigned int pack2bf(float a, float b) {
    return (unsigned int)f2bf(a) | ((unsigned int)f2bf(b) << 16);
}
__device__ __forceinline__ void gload16(const ushort_t* g, ushort_t* l) {
    __builtin_amdgcn_global_load_lds(
        (const __attribute__((address_space(1))) unsigned int*)g,
        (__attribute__((address_space(3))) unsigned int*)l, 16, 0, 0);
}
__device__ __forceinline__ f32x16 zero16() {
    f32x16 z;
#pragma unroll
    for (int i = 0; i < 16; ++i) z[i] = 0.f;
    return z;
}

// ---------------- fused small prep: P^T cvt + weight cvts + W2 ----------------
__global__ __launch_bounds__(256) void prep_small(const float* __restrict__ P,
                                                  const float* __restrict__ thw,
                                                  const float* __restrict__ phw,
                                                  const float* __restrict__ ow,
                                                  const float* __restrict__ gw,
                                                  ushort_t* __restrict__ pT,
                                                  ushort_t* __restrict__ thc,
                                                  ushort_t* __restrict__ phc,
                                                  ushort_t* __restrict__ w2c) {
    int blk = blockIdx.x;
    int t = threadIdx.x;
    __shared__ float Xs[64][68];
    if (blk < 512) {          // ---- P^T chunked cvt (N=1024) ----
        const int N = 1024;
        int bx = blk & 15, by = (blk >> 4) & 3, b = blk >> 6;
        int n0 = bx * 64, c0 = by * 64;
        const float* Xb = P + ((size_t)b * 256 + c0) * N + n0;
        int cl = t >> 4, nl = (t & 15) * 4;
#pragma unroll
        for (int ci = 0; ci < 4; ++ci) {
            int c = ci * 16 + cl;
            *(float4*)&Xs[c][nl] = *(const float4*)(Xb + (size_t)c * N + nl);
        }
        __syncthreads();
        ushort_t* xb = pT + (size_t)b * ((size_t)N * 256);
        int nl2 = t & 63, cgb = t >> 6;
#pragma unroll
        for (int cp = 0; cp < 2; ++cp) {
            int cg = cp * 4 + cgb;
            int cb = c0 + cg * 8;
            int n = n0 + nl2;
            short8 v;
#pragma unroll
            for (int u = 0; u < 8; ++u) v[u] = (short)f2bf(Xs[cg * 8 + u][nl2]);
            size_t i16 = ((size_t)(n >> 5) * 16 + (cb >> 4)) * 64 + ((cb >> 3) & 1) * 32 + (n & 31);
            *(short8*)(xb + i16 * 8) = v;
        }
    } else if (blk < 1024) {  // ---- theta/phi weight -> A-chunk layout ----
        int r = blk - 512;
        int which = r >> 8;
        int e = r & 255, c = t;
        const float* src = which ? phw : thw;
        ushort_t* dst = which ? phc : thc;
        int idx = ((((e >> 5) * 16 + (c >> 4)) * 64 + ((c >> 3) & 1) * 32 + (e & 31)) << 3) + (c & 7);
        dst[idx] = f2bf(src[e * 256 + c]);
    } else {                  // ---- W2 = out_w @ g_w rows + chunk cvt ----
        int c0 = (blk - 1024) * 8;
        float acc[8] = {};
        for (int e = 0; e < 256; ++e) {
            float g = gw[e * 256 + t];
#pragma unroll
            for (int i = 0; i < 8; ++i) acc[i] += ow[(c0 + i) * 256 + e] * g;
        }
#pragma unroll
        for (int i = 0; i < 8; ++i) {
            int c = c0 + i, k = t;
            int idx = ((((c >> 5) * 16 + (k >> 4)) * 64 + ((k >> 3) & 1) * 32 + (c & 31)) << 3) + (k & 7);
            w2c[idx] = f2bf(acc[i]);
        }
    }
}

// ---------------- MFMA projection, phi/gV only (128 blocks) ----------------
// role0 (blk<64):  phiA = phi_w @ P     kv-chunk layout
// role1 (64..127): gVx  = W2 @ P        V^T chunk layout
__global__ __launch_bounds__(256, 2) void proj_mfma(const ushort_t* __restrict__ phc,
                                                    const ushort_t* __restrict__ w2c,
                                                    const ushort_t* __restrict__ pT,
                                                    ushort_t* __restrict__ phiA,
                                                    ushort_t* __restrict__ gVx) {
    int blk = blockIdx.x;
    int tid = threadIdx.x, lane = tid & 63, wid = tid >> 6;
    int l31 = lane & 31, lh = lane >> 5;
    int role = blk >> 6;
    int r = blk & 63, b = r & 7, nt = r >> 3;
    const ushort_t* Wc = role ? w2c : phc;
    const ushort_t* xTb = pT + (size_t)b * 262144;
    ushort_t* outp = (role ? gVx : phiA) + (size_t)b * 262144;
    const int n0 = nt * 128 + wid * 32;
    const int ncr = (n0 >> 5) * 16;

    f32x16 o[8];
#pragma unroll
    for (int f = 0; f < 8; ++f) o[f] = zero16();

#pragma unroll
    for (int ks = 0; ks < 16; ++ks) {
        short8 xf = *(const short8*)(xTb + ((size_t)(ncr + ks) * 64 + lane) * 8);
#pragma unroll
        for (int f = 0; f < 8; ++f) {
            short8 wf = *(const short8*)(Wc + ((size_t)(f * 16 + ks) * 64 + lane) * 8);
            o[f] = __builtin_amdgcn_mfma_f32_32x32x16_bf16(wf, xf, o[f], 0, 0, 0);
        }
    }

    if (!role) {
#pragma unroll
        for (int f = 0; f < 8; ++f) {
#pragma unroll
            for (int rq = 0; rq < 4; ++rq) {
                uint2 st;
                st.x = pack2bf(o[f][4 * rq + 0], o[f][4 * rq + 1]);
                st.y = pack2bf(o[f][4 * rq + 2], o[f][4 * rq + 3]);
                size_t addr = ((size_t)(ncr + f * 2 + (rq >> 1)) * 64 + l31 + 32 * (rq & 1)) * 8 + 4 * lh;
                *(uint2*)(outp + addr) = st;
            }
        }
    } else {
        int kvq = (n0 >> 4) + (l31 >> 4);
        int lhw = 32 * ((l31 >> 3) & 1);
        int kl = l31 & 7;
#pragma unroll
        for (int f = 0; f < 8; ++f) {
#pragma unroll
            for (int r2 = 0; r2 < 16; ++r2) {
                int crow = (r2 & 3) + 8 * (r2 >> 2) + 4 * lh;
                size_t addr = ((size_t)(f * 64 + kvq) * 64 + crow + lhw) * 8 + kl;
                outp[addr] = f2bf(o[f][r2]);
            }
        }
    }
}

// ---------------- attn8: fused theta-proj prologue + C-copy + flash loop ----------------
// 8 waves: waves 0-3 q-groups x even kv tiles (h=0); 4-7 x odd tiles (h=1).
// Prologue: C slice -> out copy + LDS[256][132] fp32 -> theta proj (thWc) -> qf[16].
// Main loop: K staged 2 ahead, V 1 ahead; 2-ring each; one barrier per region.
__global__ __launch_bounds__(512, 2) void attn8(const ushort_t* __restrict__ thc,
                                                const ushort_t* __restrict__ phiA,
                                                const ushort_t* __restrict__ gVx,
                                                const float* __restrict__ Cf,
                                                float* __restrict__ out) {
    const int b = blockIdx.x & 7, qt = blockIdx.x >> 3;   // batch == XCD
    const int tid = threadIdx.x, lane = tid & 63, wid = tid >> 6;
    const int l31 = lane & 31, lh = lane >> 5;
    const int h = wid >> 2, qg = wid & 3;

    __shared__ __align__(16) ushort_t smem[67584];        // 132 KB (prologue fp32 view)
    __shared__ float rlS[4][32];

    const ushort_t* phA = phiA + (size_t)b * 262144;
    const ushort_t* gVb = gVx + (size_t)b * 262144;

    // ================= prologue: C load + copy + theta projection =================
    {
        float* Xf = (float*)smem;                         // [256][132]
        const float* Cb = Cf + (size_t)b * 1048576 + (size_t)qt * 128;
        float* outC = out + (size_t)b * 2097152 + (size_t)qt * 128;
#pragma unroll
        for (int i = 0; i < 16; ++i) {
            int idx = i * 512 + tid;                      // 8192 float4
            int r = idx >> 5, c4 = (idx & 31) * 4;
            float4 v = *(const float4*)(Cb + (size_t)r * 4096 + c4);
            *(float4*)(outC + (size_t)r * 4096 + c4) = v;
            *(float4*)(Xf + r * 132 + c4) = v;
        }
        __syncthreads();
    }

    f32x16 o[8];
#pragma unroll
    for (int f = 0; f < 8; ++f) o[f] = zero16();

    {   // theta proj: o[e-blocks][q] = thw @ C^T  (B-frag from LDS column reads)
        const float* Xf = (const float*)smem;
        const int q = qg * 32 + l31;
#pragma unroll
        for (int ks = 0; ks < 16; ++ks) {
            const int cb = ks * 16 + lh * 8;
            union PW { unsigned int u[4]; short8 v; } xw;
#pragma unroll
            for (int jj = 0; jj < 4; ++jj)
                xw.u[jj] = pack2bf(Xf[(cb + 2 * jj) * 132 + q],
                                   Xf[(cb + 2 * jj + 1) * 132 + q]);
#pragma unroll
            for (int f = 0; f < 8; ++f) {
                short8 wf = *(const short8*)(thc + ((size_t)(f * 16 + ks) * 64 + lane) * 8);
                o[f] = __builtin_amdgcn_mfma_f32_32x32x16_bf16(wf, xw.v, o[f], 0, 0, 0);
            }
        }
    }

    // repack proj output -> QK B-frags qf[16] (T12 pattern), scale log2e/16 in fp32
    short8 qf[16];
    {
        const float TH = 1.4426950408889634f / 16.0f;
#pragma unroll
        for (int f = 0; f < 8; ++f) {
#pragma unroll
            for (int u = 0; u < 2; ++u) {
                unsigned int A0 = pack2bf(o[f][8 * u + 0] * TH, o[f][8 * u + 1] * TH);
                unsigned int A1 = pack2bf(o[f][8 * u + 2] * TH, o[f][8 * u + 3] * TH);
                unsigned int B0 = pack2bf(o[f][8 * u + 4] * TH, o[f][8 * u + 5] * TH);
                unsigned int B1 = pack2bf(o[f][8 * u + 6] * TH, o[f][8 * u + 7] * TH);
                asm volatile("v_permlane32_swap_b32 %0, %1" : "+v"(A0), "+v"(B0));
                asm volatile("v_permlane32_swap_b32 %0, %1" : "+v"(A1), "+v"(B1));
                union PW { unsigned int u[4]; short8 v; } pw;
                pw.u[0] = A0; pw.u[1] = A1; pw.u[2] = B0; pw.u[3] = B1;
                qf[f * 2 + u] = pw.v;
            }
        }
#pragma unroll
        for (int f = 0; f < 8; ++f) o[f] = zero16();
    }
    __syncthreads();   // all prologue LDS reads done before staging overwrites smem

    // ================= main flash loop (attn7 structure, no copy) =================
    auto stageK = [&](int j) {
        if ((wid & 2) == 0) {
            int hh = wid >> 2;
            const ushort_t* src = phA + (size_t)(2 * j + hh) * 8192 + (wid & 1) * 4096 + lane * 8;
            ushort_t* dst = smem + hh * 16384 + (j & 1) * 8192 + (wid & 1) * 4096;
#pragma unroll
            for (int i = 0; i < 8; ++i) gload16(src + i * 512, dst + i * 512);
        }
    };
    auto stageV = [&](int j) {
        if ((wid & 2) == 2) {
            int hh = wid >> 2;
#pragma unroll
            for (int cg2 = 0; cg2 < 4; ++cg2) {
                int cg = (wid & 1) * 4 + cg2;
#pragma unroll
                for (int jj = 0; jj < 2; ++jj) {
                    const ushort_t* src =
                        gVb + ((size_t)(cg * 64 + 4 * j + 2 * hh + jj) * 64 + lane) * 8;
                    ushort_t* dst = smem + 32768 + hh * 16384 + (j & 1) * 8192 + cg * 1024 + jj * 512;
                    gload16(src, dst);
                }
            }
        }
    };

    stageK(0); stageK(1); stageV(0);

    float rl = 0.f;

    asm volatile("s_waitcnt vmcnt(0)" ::: "memory");
    __builtin_amdgcn_s_barrier();
    __builtin_amdgcn_sched_barrier(0);

    // QK(0)
    f32x16 s = zero16();
    {
        const ushort_t* Kb = smem + h * 16384;            // K[h][0]
#pragma unroll
        for (int ks = 0; ks < 16; ++ks) {
            short8 kf = *(const short8*)(Kb + (size_t)ks * 512 + lane * 8);
            s = __builtin_amdgcn_mfma_f32_32x32x16_bf16(kf, qf[ks], s, 0, 0, 0);
        }
    }

    for (int it = 0; it < 16; ++it) {
        asm volatile("s_waitcnt vmcnt(0)" ::: "memory");
        __builtin_amdgcn_s_barrier();
        __builtin_amdgcn_sched_barrier(0);
        if (it < 14) stageK(it + 2);
        if (it < 15) stageV(it + 1);

        // ---- no-max softmax: p = exp2(s), rl += sum ----
        float ps = 0.f;
#pragma unroll
        for (int r = 0; r < 16; ++r) {
            s[r] = __builtin_amdgcn_exp2f(s[r]);
            ps += s[r];
        }
        ps += __shfl_xor(ps, 32);
        rl += ps;

        // ---- T12: S-regs -> PV B-frags via cvt_pk + permlane32_swap ----
        unsigned int a0 = pack2bf(s[0], s[1]),   b0 = pack2bf(s[4], s[5]);
        unsigned int a1 = pack2bf(s[2], s[3]),   b1 = pack2bf(s[6], s[7]);
        unsigned int a2 = pack2bf(s[8], s[9]),   b2 = pack2bf(s[12], s[13]);
        unsigned int a3 = pack2bf(s[10], s[11]), b3 = pack2bf(s[14], s[15]);
        asm volatile("v_permlane32_swap_b32 %0, %1" : "+v"(a0), "+v"(b0));
        asm volatile("v_permlane32_swap_b32 %0, %1" : "+v"(a1), "+v"(b1));
        asm volatile("v_permlane32_swap_b32 %0, %1" : "+v"(a2), "+v"(b2));
        asm volatile("v_permlane32_swap_b32 %0, %1" : "+v"(a3), "+v"(b3));
        union PW { unsigned int u[4]; short8 v; };
        PW p0; p0.u[0] = a0; p0.u[1] = a1; p0.u[2] = b0; p0.u[3] = b1;
        PW p1; p1.u[0] = a2; p1.u[1] = a3; p1.u[2] = b2; p1.u[3] = b3;

        // ---- PV(it) || QK(it+1): independent MFMA streams ----
        const ushort_t* Vb = smem + 32768 + h * 16384 + (it & 1) * 8192;
        const ushort_t* Kb = smem + h * 16384 + ((it + 1) & 1) * 8192;
        __builtin_amdgcn_s_setprio(1);
        if (it < 15) {
            f32x16 sn = zero16();
#pragma unroll
            for (int ks2 = 0; ks2 < 2; ++ks2) {
                short8 pf = ks2 ? p1.v : p0.v;
#pragma unroll
                for (int f = 0; f < 8; ++f) {
                    short8 vf = *(const short8*)(Vb + (size_t)f * 1024 + ks2 * 512 + lane * 8);
                    o[f] = __builtin_amdgcn_mfma_f32_32x32x16_bf16(vf, pf, o[f], 0, 0, 0);
                    int ks = ks2 * 8 + f;
                    short8 kf = *(const short8*)(Kb + (size_t)ks * 512 + lane * 8);
                    sn = __builtin_amdgcn_mfma_f32_32x32x16_bf16(kf, qf[ks], sn, 0, 0, 0);
                }
            }
            s = sn;
        } else {
#pragma unroll
            for (int ks2 = 0; ks2 < 2; ++ks2) {
                short8 pf = ks2 ? p1.v : p0.v;
#pragma unroll
                for (int f = 0; f < 8; ++f) {
                    short8 vf = *(const short8*)(Vb + (size_t)f * 1024 + ks2 * 512 + lane * 8);
                    o[f] = __builtin_amdgcn_mfma_f32_32x32x16_bf16(vf, pf, o[f], 0, 0, 0);
                }
            }
        }
        __builtin_amdgcn_s_setprio(0);
        __builtin_amdgcn_sched_barrier(0);
    }

    __syncthreads();   // all waves done computing before smem is reused for partials

    // ---- merge halves: waves 4-7 publish, waves 0-3 combine + store ----
    if (wid >= 4) {
        float* part = (float*)smem + (size_t)(wid - 4) * 8192;
#pragma unroll
        for (int f = 0; f < 8; ++f)
#pragma unroll
            for (int r = 0; r < 16; ++r) {
                int e = f * 32 + (r & 3) + 8 * (r >> 2) + 4 * lh;
                part[e * 32 + l31] = o[f][r];
            }
        if (lane < 32) rlS[wid - 4][l31] = rl;
    }
    __syncthreads();
    if (wid < 4) {
        float inv = 1.f / (rl + rlS[wid][l31]);
        const float* part = (const float*)smem + (size_t)wid * 8192;
        float* ob = out + (size_t)b * 2097152 + (size_t)256 * 4096 + qt * 128 + qg * 32 + l31;
#pragma unroll
        for (int f = 0; f < 8; ++f)
#pragma unroll
            for (int r = 0; r < 16; ++r) {
                int e = f * 32 + (r & 3) + 8 * (r >> 2) + 4 * lh;
                ob[(size_t)e * 4096] = (o[f][r] + part[e * 32 + l31]) * inv;
            }
    }
}

// ---------------- launch ----------------

extern "C" void kernel_launch(void* const* d_in, const int* in_sizes, int n_in,
                              void* d_out, int out_size, void* d_ws, size_t ws_size,
                              hipStream_t stream) {
    const float* C       = (const float*)d_in[0];
    const float* P       = (const float*)d_in[1];
    const float* theta_w = (const float*)d_in[2];
    const float* phi_w   = (const float*)d_in[3];
    const float* g_w     = (const float*)d_in[4];
    const float* out_w   = (const float*)d_in[5];
    float* out = (float*)d_out;

    ushort_t* ws = (ushort_t*)d_ws;
    ushort_t* phiA = ws;                          // 2,097,152
    ushort_t* pT   = ws + 2097152;                // 2,097,152
    ushort_t* gVx  = ws + 4194304;                // 2,097,152
    ushort_t* thWc = ws + 6291456;                // 65,536
    ushort_t* phWc = ws + 6356992;                // 65,536
    ushort_t* w2c  = ws + 6422528;                // 65,536

    prep_small<<<1056, 256, 0, stream>>>(P, theta_w, phi_w, out_w, g_w,
                                         pT, thWc, phWc, w2c);
    proj_mfma<<<128, 256, 0, stream>>>(phWc, w2c, pT, phiA, gVx);
    attn8<<<256, 512, 0, stream>>>(thWc, phiA, gVx, C, out);
}

// Round 10
// 117.624 us; speedup vs baseline: 1.0472x; 1.0472x over previous
//
#include <hip/hip_runtime.h>

// CrossModalAttention  B=8, CQ=CKV=E=256, Nq=4096, Nkv=1024
// out = concat([C, (out_w@g_w@P) @ softmax(thetaC^T @ phiP / 16)^T], axis=1)

typedef __attribute__((ext_vector_type(8))) short short8;   // 8 bf16 raw
typedef __attribute__((ext_vector_type(16))) float f32x16;
typedef unsigned short ushort_t;

__device__ __forceinline__ unsigned short f2bf(float f) {
    unsigned int u = __float_as_uint(f);
    u += 0x7FFFu + ((u >> 16) & 1u);            // RNE
    return (unsigned short)(u >> 16);
}
__device__ __forceinline__ unsigned int pack2bf(float a, float b) {
    return (unsigned int)f2bf(a) | ((unsigned int)f2bf(b) << 16);
}
__device__ __forceinline__ void gload16(const ushort_t* g, ushort_t* l) {
    __builtin_amdgcn_global_load_lds(
        (const __attribute__((address_space(1))) unsigned int*)g,
        (__attribute__((address_space(3))) unsigned int*)l, 16, 0, 0);
}
__device__ __forceinline__ f32x16 zero16() {
    f32x16 z;
#pragma unroll
    for (int i = 0; i < 16; ++i) z[i] = 0.f;
    return z;
}

// ---------------- prep_all: P^T cvt + C^T cvt + weight cvts + W2 (one launch) ----
// blk [0,512):    P^T chunked cvt
// blk [512,2560): C^T chunked cvt
// blk [2560,3072): theta/phi weight -> A-chunk layout
// blk [3072,3104): W2 = out_w @ g_w + chunk cvt
__global__ __launch_bounds__(256) void prep_all(const float* __restrict__ P,
                                                const float* __restrict__ C,
                                                const float* __restrict__ thw,
                                                const float* __restrict__ phw,
                                                const float* __restrict__ ow,
                                                const float* __restrict__ gw,
                                                ushort_t* __restrict__ pT,
                                                ushort_t* __restrict__ cT,
                                                ushort_t* __restrict__ thc,
                                                ushort_t* __restrict__ phc,
                                                ushort_t* __restrict__ w2c) {
    int blk = blockIdx.x;
    int t = threadIdx.x;
    __shared__ float Xs[64][68];
    if (blk < 2560) {         // ---- X^T chunked cvt (P or C) ----
        const float* X;
        ushort_t* xT;
        int N, bx, by, b;
        if (blk < 512) {
            X = P; xT = pT; N = 1024;
            bx = blk & 15; by = (blk >> 4) & 3; b = blk >> 6;
        } else {
            int r = blk - 512;
            X = C; xT = cT; N = 4096;
            bx = r & 63; by = (r >> 6) & 3; b = r >> 8;
        }
        int n0 = bx * 64, c0 = by * 64;
        const float* Xb = X + ((size_t)b * 256 + c0) * N + n0;
        int cl = t >> 4, nl = (t & 15) * 4;
#pragma unroll
        for (int ci = 0; ci < 4; ++ci) {
            int c = ci * 16 + cl;
            *(float4*)&Xs[c][nl] = *(const float4*)(Xb + (size_t)c * N + nl);
        }
        __syncthreads();
        ushort_t* xb = xT + (size_t)b * ((size_t)N * 256);
        int nl2 = t & 63, cgb = t >> 6;
#pragma unroll
        for (int cp = 0; cp < 2; ++cp) {
            int cg = cp * 4 + cgb;
            int cb = c0 + cg * 8;
            int n = n0 + nl2;
            short8 v;
#pragma unroll
            for (int u = 0; u < 8; ++u) v[u] = (short)f2bf(Xs[cg * 8 + u][nl2]);
            size_t i16 = ((size_t)(n >> 5) * 16 + (cb >> 4)) * 64 + ((cb >> 3) & 1) * 32 + (n & 31);
            *(short8*)(xb + i16 * 8) = v;
        }
    } else if (blk < 3072) {  // ---- theta/phi weight -> A-chunk layout ----
        int r = blk - 2560;
        int which = r >> 8;
        int e = r & 255, c = t;
        const float* src = which ? phw : thw;
        ushort_t* dst = which ? phc : thc;
        int idx = ((((e >> 5) * 16 + (c >> 4)) * 64 + ((c >> 3) & 1) * 32 + (e & 31)) << 3) + (c & 7);
        dst[idx] = f2bf(src[e * 256 + c]);
    } else {                  // ---- W2 = out_w @ g_w rows + chunk cvt ----
        int c0 = (blk - 3072) * 8;
        float acc[8] = {};
        for (int e = 0; e < 256; ++e) {
            float g = gw[e * 256 + t];
#pragma unroll
            for (int i = 0; i < 8; ++i) acc[i] += ow[(c0 + i) * 256 + e] * g;
        }
#pragma unroll
        for (int i = 0; i < 8; ++i) {
            int c = c0 + i, k = t;
            int idx = ((((c >> 5) * 16 + (k >> 4)) * 64 + ((k >> 3) & 1) * 32 + (c & 31)) << 3) + (k & 7);
            w2c[idx] = f2bf(acc[i]);
        }
    }
}

// ---------------- unified MFMA projection, 128-thr blocks (load-balanced) ----------
// blk [0,512):    thetaA = theta_w @ C  (scale log2e/16)   q-chunk layout
// blk [512,640):  phiA   = phi_w @ P                       kv-chunk layout
// blk [640,768):  gVx    = W2 @ P                          V^T chunk layout
__global__ __launch_bounds__(128, 2) void proj_mfma(const ushort_t* __restrict__ thc,
                                                    const ushort_t* __restrict__ phc,
                                                    const ushort_t* __restrict__ w2c,
                                                    const ushort_t* __restrict__ cT,
                                                    const ushort_t* __restrict__ pT,
                                                    ushort_t* __restrict__ thetaA,
                                                    ushort_t* __restrict__ phiA,
                                                    ushort_t* __restrict__ gVx) {
    int blk = blockIdx.x;
    int tid = threadIdx.x, lane = tid & 63, wid = tid >> 6;   // 2 waves
    int l31 = lane & 31, lh = lane >> 5;
    int role, b, nt;
    const ushort_t *Wc, *xTb;
    ushort_t* outp;
    float scale = 1.f;
    if (blk < 512) {
        role = 0; b = blk & 7; nt = blk >> 3;                 // 64 q-tiles of 64
        Wc = thc; xTb = cT + (size_t)b * 1048576; outp = thetaA + (size_t)b * 1048576;
        scale = 1.4426950408889634f / 16.0f;
    } else if (blk < 640) {
        int r = blk - 512; role = 1; b = r & 7; nt = r >> 3;  // 16 kv-tiles of 64
        Wc = phc; xTb = pT + (size_t)b * 262144; outp = phiA + (size_t)b * 262144;
    } else {
        int r = blk - 640; role = 2; b = r & 7; nt = r >> 3;
        Wc = w2c; xTb = pT + (size_t)b * 262144; outp = gVx + (size_t)b * 262144;
    }
    const int n0 = nt * 64 + wid * 32;
    const int ncr = (n0 >> 5) * 16;

    f32x16 o[8];
#pragma unroll
    for (int f = 0; f < 8; ++f) o[f] = zero16();

#pragma unroll
    for (int ks = 0; ks < 16; ++ks) {
        short8 xf = *(const short8*)(xTb + ((size_t)(ncr + ks) * 64 + lane) * 8);
#pragma unroll
        for (int f = 0; f < 8; ++f) {
            short8 wf = *(const short8*)(Wc + ((size_t)(f * 16 + ks) * 64 + lane) * 8);
            o[f] = __builtin_amdgcn_mfma_f32_32x32x16_bf16(wf, xf, o[f], 0, 0, 0);
        }
    }

    if (role < 2) {
#pragma unroll
        for (int f = 0; f < 8; ++f) {
#pragma unroll
            for (int rq = 0; rq < 4; ++rq) {
                uint2 st;
                st.x = pack2bf(o[f][4 * rq + 0] * scale, o[f][4 * rq + 1] * scale);
                st.y = pack2bf(o[f][4 * rq + 2] * scale, o[f][4 * rq + 3] * scale);
                size_t addr = ((size_t)(ncr + f * 2 + (rq >> 1)) * 64 + l31 + 32 * (rq & 1)) * 8 + 4 * lh;
                *(uint2*)(outp + addr) = st;
            }
        }
    } else {
        int kvq = (n0 >> 4) + (l31 >> 4);
        int lhw = 32 * ((l31 >> 3) & 1);
        int kl = l31 & 7;
#pragma unroll
        for (int f = 0; f < 8; ++f) {
#pragma unroll
            for (int r2 = 0; r2 < 16; ++r2) {
                int crow = (r2 & 3) + 8 * (r2 >> 2) + 4 * lh;
                size_t addr = ((size_t)(f * 64 + kvq) * 64 + crow + lhw) * 8 + kl;
                outp[addr] = f2bf(o[f][r2]);
            }
        }
    }
}

// ---------------- attn7: no-max softmax + C-copy fold + PV||QK pipeline ----------------
// (round-8 proven version, verbatim)
__global__ __launch_bounds__(512, 2) void attn7(const ushort_t* __restrict__ thetaA,
                                                const ushort_t* __restrict__ phiA,
                                                const ushort_t* __restrict__ gVx,
                                                const float* __restrict__ Cf,
                                                float* __restrict__ out) {
    const int b = blockIdx.x & 7, qt = blockIdx.x >> 3;   // batch == XCD
    const int tid = threadIdx.x, lane = tid & 63, wid = tid >> 6;
    const int l31 = lane & 31, lh = lane >> 5;
    const int h = wid >> 2, qg = wid & 3;

    __shared__ __align__(16) ushort_t smem[65536];        // 128 KB
    __shared__ float rlS[4][32];

    const ushort_t* thA = thetaA + (size_t)b * 1048576;
    const ushort_t* phA = phiA + (size_t)b * 262144;
    const ushort_t* gVb = gVx + (size_t)b * 262144;

    auto stageK = [&](int j) {
        if ((wid & 2) == 0) {
            int hh = wid >> 2;
            const ushort_t* src = phA + (size_t)(2 * j + hh) * 8192 + (wid & 1) * 4096 + lane * 8;
            ushort_t* dst = smem + hh * 16384 + (j & 1) * 8192 + (wid & 1) * 4096;
#pragma unroll
            for (int i = 0; i < 8; ++i) gload16(src + i * 512, dst + i * 512);
        }
    };
    auto stageV = [&](int j) {
        if ((wid & 2) == 2) {
            int hh = wid >> 2;
#pragma unroll
            for (int cg2 = 0; cg2 < 4; ++cg2) {
                int cg = (wid & 1) * 4 + cg2;
#pragma unroll
                for (int jj = 0; jj < 2; ++jj) {
                    const ushort_t* src =
                        gVb + ((size_t)(cg * 64 + 4 * j + 2 * hh + jj) * 64 + lane) * 8;
                    ushort_t* dst = smem + 32768 + hh * 16384 + (j & 1) * 8192 + cg * 1024 + jj * 512;
                    gload16(src, dst);
                }
            }
        }
    };

    stageK(0); stageK(1); stageV(0);

    short8 qf[16];
    {
        const int qcr = (qt * 4 + qg) * 16;
#pragma unroll
        for (int ks = 0; ks < 16; ++ks)
            qf[ks] = *(const short8*)(thA + ((size_t)(qcr + ks) * 64 + lane) * 8);
    }

    f32x16 o[8];
#pragma unroll
    for (int f = 0; f < 8; ++f) o[f] = zero16();
    float rl = 0.f;

    // C-copy fold bases: row(it) = it*16 + 2*wid + lh, col = qt*128 + l31*4
    const size_t cbase = (size_t)b * 1048576 + (size_t)qt * 128 + (size_t)l31 * 4;
    const size_t dofs = (size_t)b * 1048576;   // out batch stride 2M vs C 1M
    size_t cpo = 0;
    float4 cpv;

    asm volatile("s_waitcnt vmcnt(0)" ::: "memory");
    __builtin_amdgcn_s_barrier();
    __builtin_amdgcn_sched_barrier(0);

    // QK(0)
    f32x16 s = zero16();
    {
        const ushort_t* Kb = smem + h * 16384;            // K[h][0]
#pragma unroll
        for (int ks = 0; ks < 16; ++ks) {
            short8 kf = *(const short8*)(Kb + (size_t)ks * 512 + lane * 8);
            s = __builtin_amdgcn_mfma_f32_32x32x16_bf16(kf, qf[ks], s, 0, 0, 0);
        }
    }

    for (int it = 0; it < 16; ++it) {
        asm volatile("s_waitcnt vmcnt(0)" ::: "memory");
        __builtin_amdgcn_s_barrier();
        __builtin_amdgcn_sched_barrier(0);
        if (it < 14) stageK(it + 2);
        if (it < 15) stageV(it + 1);

        // ---- C-copy fold: store prev region's slice, load this region's ----
        if (it > 0) *(float4*)(out + cpo + dofs) = cpv;
        cpo = cbase + (size_t)(it * 16 + 2 * wid + lh) * 4096;
        cpv = *(const float4*)(Cf + cpo);

        // ---- no-max softmax: p = exp2(s), rl += sum ----
        float ps = 0.f;
#pragma unroll
        for (int r = 0; r < 16; ++r) {
            s[r] = __builtin_amdgcn_exp2f(s[r]);
            ps += s[r];
        }
        ps += __shfl_xor(ps, 32);
        rl += ps;

        // ---- T12: S-regs -> PV B-frags via cvt_pk + permlane32_swap ----
        unsigned int a0 = pack2bf(s[0], s[1]),   b0 = pack2bf(s[4], s[5]);
        unsigned int a1 = pack2bf(s[2], s[3]),   b1 = pack2bf(s[6], s[7]);
        unsigned int a2 = pack2bf(s[8], s[9]),   b2 = pack2bf(s[12], s[13]);
        unsigned int a3 = pack2bf(s[10], s[11]), b3 = pack2bf(s[14], s[15]);
        asm volatile("v_permlane32_swap_b32 %0, %1" : "+v"(a0), "+v"(b0));
        asm volatile("v_permlane32_swap_b32 %0, %1" : "+v"(a1), "+v"(b1));
        asm volatile("v_permlane32_swap_b32 %0, %1" : "+v"(a2), "+v"(b2));
        asm volatile("v_permlane32_swap_b32 %0, %1" : "+v"(a3), "+v"(b3));
        union PW { unsigned int u[4]; short8 v; };
        PW p0; p0.u[0] = a0; p0.u[1] = a1; p0.u[2] = b0; p0.u[3] = b1;
        PW p1; p1.u[0] = a2; p1.u[1] = a3; p1.u[2] = b2; p1.u[3] = b3;

        // ---- PV(it) || QK(it+1): independent MFMA streams ----
        const ushort_t* Vb = smem + 32768 + h * 16384 + (it & 1) * 8192;
        const ushort_t* Kb = smem + h * 16384 + ((it + 1) & 1) * 8192;
        __builtin_amdgcn_s_setprio(1);
        if (it < 15) {
            f32x16 sn = zero16();
#pragma unroll
            for (int ks2 = 0; ks2 < 2; ++ks2) {
                short8 pf = ks2 ? p1.v : p0.v;
#pragma unroll
                for (int f = 0; f < 8; ++f) {
                    short8 vf = *(const short8*)(Vb + (size_t)f * 1024 + ks2 * 512 + lane * 8);
                    o[f] = __builtin_amdgcn_mfma_f32_32x32x16_bf16(vf, pf, o[f], 0, 0, 0);
                    int ks = ks2 * 8 + f;
                    short8 kf = *(const short8*)(Kb + (size_t)ks * 512 + lane * 8);
                    sn = __builtin_amdgcn_mfma_f32_32x32x16_bf16(kf, qf[ks], sn, 0, 0, 0);
                }
            }
            s = sn;
        } else {
#pragma unroll
            for (int ks2 = 0; ks2 < 2; ++ks2) {
                short8 pf = ks2 ? p1.v : p0.v;
#pragma unroll
                for (int f = 0; f < 8; ++f) {
                    short8 vf = *(const short8*)(Vb + (size_t)f * 1024 + ks2 * 512 + lane * 8);
                    o[f] = __builtin_amdgcn_mfma_f32_32x32x16_bf16(vf, pf, o[f], 0, 0, 0);
                }
            }
        }
        __builtin_amdgcn_s_setprio(0);
        __builtin_amdgcn_sched_barrier(0);
    }

    *(float4*)(out + cpo + dofs) = cpv;   // last copy slice (region 15)

    __syncthreads();   // all waves done computing before smem is reused for partials

    // ---- merge halves: waves 4-7 publish, waves 0-3 combine + store ----
    if (wid >= 4) {
        float* part = (float*)smem + (size_t)(wid - 4) * 8192;
#pragma unroll
        for (int f = 0; f < 8; ++f)
#pragma unroll
            for (int r = 0; r < 16; ++r) {
                int e = f * 32 + (r & 3) + 8 * (r >> 2) + 4 * lh;
                part[e * 32 + l31] = o[f][r];
            }
        if (lane < 32) rlS[wid - 4][l31] = rl;
    }
    __syncthreads();
    if (wid < 4) {
        float inv = 1.f / (rl + rlS[wid][l31]);
        const float* part = (const float*)smem + (size_t)wid * 8192;
        float* ob = out + (size_t)b * 2097152 + (size_t)256 * 4096 + qt * 128 + qg * 32 + l31;
#pragma unroll
        for (int f = 0; f < 8; ++f)
#pragma unroll
            for (int r = 0; r < 16; ++r) {
                int e = f * 32 + (r & 3) + 8 * (r >> 2) + 4 * lh;
                ob[(size_t)e * 4096] = (o[f][r] + part[e * 32 + l31]) * inv;
            }
    }
}

// ---------------- launch ----------------

extern "C" void kernel_launch(void* const* d_in, const int* in_sizes, int n_in,
                              void* d_out, int out_size, void* d_ws, size_t ws_size,
                              hipStream_t stream) {
    const float* C       = (const float*)d_in[0];
    const float* P       = (const float*)d_in[1];
    const float* theta_w = (const float*)d_in[2];
    const float* phi_w   = (const float*)d_in[3];
    const float* g_w     = (const float*)d_in[4];
    const float* out_w   = (const float*)d_in[5];
    float* out = (float*)d_out;

    ushort_t* ws = (ushort_t*)d_ws;
    ushort_t* thetaA = ws;                        // 8,388,608
    ushort_t* cT     = ws + 8388608;              // 8,388,608
    ushort_t* phiA   = ws + 16777216;             // 2,097,152
    ushort_t* pT     = ws + 18874368;              // 2,097,152
    ushort_t* gVx    = ws + 20971520;             // 2,097,152
    ushort_t* thWc   = ws + 23068672;             // 65,536
    ushort_t* phWc   = ws + 23134208;             // 65,536
    ushort_t* w2c    = ws + 23199744;             // 65,536

    prep_all<<<3104, 256, 0, stream>>>(P, C, theta_w, phi_w, out_w, g_w,
                                       pT, cT, thWc, phWc, w2c);
    proj_mfma<<<768, 128, 0, stream>>>(thWc, phWc, w2c, cT, pT, thetaA, phiA, gVx);
    attn7<<<256, 512, 0, stream>>>(thetaA, phiA, gVx, C, out);
}

// Round 11
// 111.550 us; speedup vs baseline: 1.1042x; 1.0544x over previous
//
#include <hip/hip_runtime.h>

// CrossModalAttention  B=8, CQ=CKV=E=256, Nq=4096, Nkv=1024
// out = concat([C, (out_w@g_w@P) @ softmax(thetaC^T @ phiP / 16)^T], axis=1)

typedef __attribute__((ext_vector_type(8))) short short8;   // 8 bf16 raw
typedef __attribute__((ext_vector_type(16))) float f32x16;
typedef unsigned short ushort_t;

__device__ __forceinline__ unsigned short f2bf(float f) {
    unsigned int u = __float_as_uint(f);
    u += 0x7FFFu + ((u >> 16) & 1u);            // RNE
    return (unsigned short)(u >> 16);
}
__device__ __forceinline__ unsigned int pack2bf(float a, float b) {
    return (unsigned int)f2bf(a) | ((unsigned int)f2bf(b) << 16);
}
__device__ __forceinline__ void gload16(const ushort_t* g, ushort_t* l) {
    __builtin_amdgcn_global_load_lds(
        (const __attribute__((address_space(1))) unsigned int*)g,
        (__attribute__((address_space(3))) unsigned int*)l, 16, 0, 0);
}
__device__ __forceinline__ f32x16 zero16() {
    f32x16 z;
#pragma unroll
    for (int i = 0; i < 16; ++i) z[i] = 0.f;
    return z;
}

// ---------------- prep_w: weight chunk cvts + W2 (tiny, weights only) ----------------
// blk [0,512):   theta/phi weight -> A-chunk layout
// blk [512,544): W2 = out_w @ g_w + chunk cvt
__global__ __launch_bounds__(256) void prep_w(const float* __restrict__ thw,
                                              const float* __restrict__ phw,
                                              const float* __restrict__ ow,
                                              const float* __restrict__ gw,
                                              ushort_t* __restrict__ thc,
                                              ushort_t* __restrict__ phc,
                                              ushort_t* __restrict__ w2c) {
    int blk = blockIdx.x;
    int t = threadIdx.x;
    if (blk < 512) {          // ---- theta/phi weight -> A-chunk layout ----
        int which = blk >> 8;
        int e = blk & 255, c = t;
        const float* src = which ? phw : thw;
        ushort_t* dst = which ? phc : thc;
        int idx = ((((e >> 5) * 16 + (c >> 4)) * 64 + ((c >> 3) & 1) * 32 + (e & 31)) << 3) + (c & 7);
        dst[idx] = f2bf(src[e * 256 + c]);
    } else {                  // ---- W2 = out_w @ g_w rows + chunk cvt ----
        int c0 = (blk - 512) * 8;
        float acc[8] = {};
        for (int e = 0; e < 256; ++e) {
            float g = gw[e * 256 + t];
#pragma unroll
            for (int i = 0; i < 8; ++i) acc[i] += ow[(c0 + i) * 256 + e] * g;
        }
#pragma unroll
        for (int i = 0; i < 8; ++i) {
            int c = c0 + i, k = t;
            int idx = ((((c >> 5) * 16 + (k >> 4)) * 64 + ((k >> 3) & 1) * 32 + (c & 31)) << 3) + (k & 7);
            w2c[idx] = f2bf(acc[i]);
        }
    }
}

// ---------------- proj_all: fp32 X-slice -> LDS -> pack B-frags -> MFMA ----------------
// blk [0,512):   thetaA = theta_w @ C  (scale log2e/16)   q-chunk layout   (X = C, N=4096)
// blk [512,640): phiA   = phi_w @ P                       kv-chunk layout  (X = P, N=1024)
// blk [640,768): gVx    = W2 @ P                          V^T chunk layout (X = P, N=1024)
// Block: 256 thr, 4 waves = (2 q-halves) x (2 e-halves); 64 n-cols, 256 channels.
__global__ __launch_bounds__(256, 2) void proj_all(const ushort_t* __restrict__ thc,
                                                   const ushort_t* __restrict__ phc,
                                                   const ushort_t* __restrict__ w2c,
                                                   const float* __restrict__ C,
                                                   const float* __restrict__ P,
                                                   ushort_t* __restrict__ thetaA,
                                                   ushort_t* __restrict__ phiA,
                                                   ushort_t* __restrict__ gVx) {
    __shared__ float Xs[256][68];     // 68 KB: [channel][n], +4 pad
    int blk = blockIdx.x;
    int tid = threadIdx.x, lane = tid & 63, wid = tid >> 6;
    int l31 = lane & 31, lh = lane >> 5;
    const int wq = wid & 1, we = wid >> 1;   // q-half, e-half

    int role, b, nt, N;
    const ushort_t* Wc;
    const float* Xg;
    ushort_t* outp;
    float scale = 1.f;
    if (blk < 512) {
        role = 0; b = blk & 7; nt = blk >> 3;
        Wc = thc; Xg = C + (size_t)b * 1048576; outp = thetaA + (size_t)b * 1048576;
        N = 4096; scale = 1.4426950408889634f / 16.0f;
    } else if (blk < 640) {
        int r = blk - 512; role = 1; b = r & 7; nt = r >> 3;
        Wc = phc; Xg = P + (size_t)b * 262144; outp = phiA + (size_t)b * 262144;
        N = 1024;
    } else {
        int r = blk - 640; role = 2; b = r & 7; nt = r >> 3;
        Wc = w2c; Xg = P + (size_t)b * 262144; outp = gVx + (size_t)b * 262144;
        N = 1024;
    }

    // ---- load 256ch x 64n fp32 slice (coalesced) ----
    {
        const float* Xb = Xg + nt * 64;
#pragma unroll
        for (int i = 0; i < 16; ++i) {
            int idx = i * 256 + tid;          // 4096 float4
            int row = idx >> 4, c4 = (idx & 15) * 4;
            *(float4*)&Xs[row][c4] = *(const float4*)(Xb + (size_t)row * N + c4);
        }
    }
    __syncthreads();

    const int n0 = nt * 64 + wq * 32;
    const int ncr = (n0 >> 5) * 16;
    const int q = wq * 32 + l31;              // local n-col for this lane

    f32x16 o[4];
#pragma unroll
    for (int f = 0; f < 4; ++f) o[f] = zero16();

#pragma unroll
    for (int ks = 0; ks < 16; ++ks) {
        const int cb = ks * 16 + lh * 8;
        union PW { unsigned int u[4]; short8 v; } xw;
#pragma unroll
        for (int j = 0; j < 4; ++j)
            xw.u[j] = pack2bf(Xs[cb + 2 * j][q], Xs[cb + 2 * j + 1][q]);
#pragma unroll
        for (int f2 = 0; f2 < 4; ++f2) {
            int f = we * 4 + f2;
            short8 wf = *(const short8*)(Wc + ((size_t)(f * 16 + ks) * 64 + lane) * 8);
            o[f2] = __builtin_amdgcn_mfma_f32_32x32x16_bf16(wf, xw.v, o[f2], 0, 0, 0);
        }
    }

    if (role < 2) {
#pragma unroll
        for (int f2 = 0; f2 < 4; ++f2) {
            int f = we * 4 + f2;
#pragma unroll
            for (int rq = 0; rq < 4; ++rq) {
                uint2 st;
                st.x = pack2bf(o[f2][4 * rq + 0] * scale, o[f2][4 * rq + 1] * scale);
                st.y = pack2bf(o[f2][4 * rq + 2] * scale, o[f2][4 * rq + 3] * scale);
                size_t addr = ((size_t)(ncr + f * 2 + (rq >> 1)) * 64 + l31 + 32 * (rq & 1)) * 8 + 4 * lh;
                *(uint2*)(outp + addr) = st;
            }
        }
    } else {
        int kvq = (n0 >> 4) + (l31 >> 4);
        int lhw = 32 * ((l31 >> 3) & 1);
        int kl = l31 & 7;
#pragma unroll
        for (int f2 = 0; f2 < 4; ++f2) {
            int f = we * 4 + f2;
#pragma unroll
            for (int r2 = 0; r2 < 16; ++r2) {
                int crow = (r2 & 3) + 8 * (r2 >> 2) + 4 * lh;
                size_t addr = ((size_t)(f * 64 + kvq) * 64 + crow + lhw) * 8 + kl;
                outp[addr] = f2bf(o[f2][r2]);
            }
        }
    }
}

// ---------------- attn7: no-max softmax + C-copy fold + PV||QK pipeline ----------------
// (round-8 proven version, verbatim)
__global__ __launch_bounds__(512, 2) void attn7(const ushort_t* __restrict__ thetaA,
                                                const ushort_t* __restrict__ phiA,
                                                const ushort_t* __restrict__ gVx,
                                                const float* __restrict__ Cf,
                                                float* __restrict__ out) {
    const int b = blockIdx.x & 7, qt = blockIdx.x >> 3;   // batch == XCD
    const int tid = threadIdx.x, lane = tid & 63, wid = tid >> 6;
    const int l31 = lane & 31, lh = lane >> 5;
    const int h = wid >> 2, qg = wid & 3;

    __shared__ __align__(16) ushort_t smem[65536];        // 128 KB
    __shared__ float rlS[4][32];

    const ushort_t* thA = thetaA + (size_t)b * 1048576;
    const ushort_t* phA = phiA + (size_t)b * 262144;
    const ushort_t* gVb = gVx + (size_t)b * 262144;

    auto stageK = [&](int j) {
        if ((wid & 2) == 0) {
            int hh = wid >> 2;
            const ushort_t* src = phA + (size_t)(2 * j + hh) * 8192 + (wid & 1) * 4096 + lane * 8;
            ushort_t* dst = smem + hh * 16384 + (j & 1) * 8192 + (wid & 1) * 4096;
#pragma unroll
            for (int i = 0; i < 8; ++i) gload16(src + i * 512, dst + i * 512);
        }
    };
    auto stageV = [&](int j) {
        if ((wid & 2) == 2) {
            int hh = wid >> 2;
#pragma unroll
            for (int cg2 = 0; cg2 < 4; ++cg2) {
                int cg = (wid & 1) * 4 + cg2;
#pragma unroll
                for (int jj = 0; jj < 2; ++jj) {
                    const ushort_t* src =
                        gVb + ((size_t)(cg * 64 + 4 * j + 2 * hh + jj) * 64 + lane) * 8;
                    ushort_t* dst = smem + 32768 + hh * 16384 + (j & 1) * 8192 + cg * 1024 + jj * 512;
                    gload16(src, dst);
                }
            }
        }
    };

    stageK(0); stageK(1); stageV(0);

    short8 qf[16];
    {
        const int qcr = (qt * 4 + qg) * 16;
#pragma unroll
        for (int ks = 0; ks < 16; ++ks)
            qf[ks] = *(const short8*)(thA + ((size_t)(qcr + ks) * 64 + lane) * 8);
    }

    f32x16 o[8];
#pragma unroll
    for (int f = 0; f < 8; ++f) o[f] = zero16();
    float rl = 0.f;

    // C-copy fold bases: row(it) = it*16 + 2*wid + lh, col = qt*128 + l31*4
    const size_t cbase = (size_t)b * 1048576 + (size_t)qt * 128 + (size_t)l31 * 4;
    const size_t dofs = (size_t)b * 1048576;   // out batch stride 2M vs C 1M
    size_t cpo = 0;
    float4 cpv;

    asm volatile("s_waitcnt vmcnt(0)" ::: "memory");
    __builtin_amdgcn_s_barrier();
    __builtin_amdgcn_sched_barrier(0);

    // QK(0)
    f32x16 s = zero16();
    {
        const ushort_t* Kb = smem + h * 16384;            // K[h][0]
#pragma unroll
        for (int ks = 0; ks < 16; ++ks) {
            short8 kf = *(const short8*)(Kb + (size_t)ks * 512 + lane * 8);
            s = __builtin_amdgcn_mfma_f32_32x32x16_bf16(kf, qf[ks], s, 0, 0, 0);
        }
    }

    for (int it = 0; it < 16; ++it) {
        asm volatile("s_waitcnt vmcnt(0)" ::: "memory");
        __builtin_amdgcn_s_barrier();
        __builtin_amdgcn_sched_barrier(0);
        if (it < 14) stageK(it + 2);
        if (it < 15) stageV(it + 1);

        // ---- C-copy fold: store prev region's slice, load this region's ----
        if (it > 0) *(float4*)(out + cpo + dofs) = cpv;
        cpo = cbase + (size_t)(it * 16 + 2 * wid + lh) * 4096;
        cpv = *(const float4*)(Cf + cpo);

        // ---- no-max softmax: p = exp2(s), rl += sum ----
        float ps = 0.f;
#pragma unroll
        for (int r = 0; r < 16; ++r) {
            s[r] = __builtin_amdgcn_exp2f(s[r]);
            ps += s[r];
        }
        ps += __shfl_xor(ps, 32);
        rl += ps;

        // ---- T12: S-regs -> PV B-frags via cvt_pk + permlane32_swap ----
        unsigned int a0 = pack2bf(s[0], s[1]),   b0 = pack2bf(s[4], s[5]);
        unsigned int a1 = pack2bf(s[2], s[3]),   b1 = pack2bf(s[6], s[7]);
        unsigned int a2 = pack2bf(s[8], s[9]),   b2 = pack2bf(s[12], s[13]);
        unsigned int a3 = pack2bf(s[10], s[11]), b3 = pack2bf(s[14], s[15]);
        asm volatile("v_permlane32_swap_b32 %0, %1" : "+v"(a0), "+v"(b0));
        asm volatile("v_permlane32_swap_b32 %0, %1" : "+v"(a1), "+v"(b1));
        asm volatile("v_permlane32_swap_b32 %0, %1" : "+v"(a2), "+v"(b2));
        asm volatile("v_permlane32_swap_b32 %0, %1" : "+v"(a3), "+v"(b3));
        union PW { unsigned int u[4]; short8 v; };
        PW p0; p0.u[0] = a0; p0.u[1] = a1; p0.u[2] = b0; p0.u[3] = b1;
        PW p1; p1.u[0] = a2; p1.u[1] = a3; p1.u[2] = b2; p1.u[3] = b3;

        // ---- PV(it) || QK(it+1): independent MFMA streams ----
        const ushort_t* Vb = smem + 32768 + h * 16384 + (it & 1) * 8192;
        const ushort_t* Kb = smem + h * 16384 + ((it + 1) & 1) * 8192;
        __builtin_amdgcn_s_setprio(1);
        if (it < 15) {
            f32x16 sn = zero16();
#pragma unroll
            for (int ks2 = 0; ks2 < 2; ++ks2) {
                short8 pf = ks2 ? p1.v : p0.v;
#pragma unroll
                for (int f = 0; f < 8; ++f) {
                    short8 vf = *(const short8*)(Vb + (size_t)f * 1024 + ks2 * 512 + lane * 8);
                    o[f] = __builtin_amdgcn_mfma_f32_32x32x16_bf16(vf, pf, o[f], 0, 0, 0);
                    int ks = ks2 * 8 + f;
                    short8 kf = *(const short8*)(Kb + (size_t)ks * 512 + lane * 8);
                    sn = __builtin_amdgcn_mfma_f32_32x32x16_bf16(kf, qf[ks], sn, 0, 0, 0);
                }
            }
            s = sn;
        } else {
#pragma unroll
            for (int ks2 = 0; ks2 < 2; ++ks2) {
                short8 pf = ks2 ? p1.v : p0.v;
#pragma unroll
                for (int f = 0; f < 8; ++f) {
                    short8 vf = *(const short8*)(Vb + (size_t)f * 1024 + ks2 * 512 + lane * 8);
                    o[f] = __builtin_amdgcn_mfma_f32_32x32x16_bf16(vf, pf, o[f], 0, 0, 0);
                }
            }
        }
        __builtin_amdgcn_s_setprio(0);
        __builtin_amdgcn_sched_barrier(0);
    }

    *(float4*)(out + cpo + dofs) = cpv;   // last copy slice (region 15)

    __syncthreads();   // all waves done computing before smem is reused for partials

    // ---- merge halves: waves 4-7 publish, waves 0-3 combine + store ----
    if (wid >= 4) {
        float* part = (float*)smem + (size_t)(wid - 4) * 8192;
#pragma unroll
        for (int f = 0; f < 8; ++f)
#pragma unroll
            for (int r = 0; r < 16; ++r) {
                int e = f * 32 + (r & 3) + 8 * (r >> 2) + 4 * lh;
                part[e * 32 + l31] = o[f][r];
            }
        if (lane < 32) rlS[wid - 4][l31] = rl;
    }
    __syncthreads();
    if (wid < 4) {
        float inv = 1.f / (rl + rlS[wid][l31]);
        const float* part = (const float*)smem + (size_t)wid * 8192;
        float* ob = out + (size_t)b * 2097152 + (size_t)256 * 4096 + qt * 128 + qg * 32 + l31;
#pragma unroll
        for (int f = 0; f < 8; ++f)
#pragma unroll
            for (int r = 0; r < 16; ++r) {
                int e = f * 32 + (r & 3) + 8 * (r >> 2) + 4 * lh;
                ob[(size_t)e * 4096] = (o[f][r] + part[e * 32 + l31]) * inv;
            }
    }
}

// ---------------- launch ----------------

extern "C" void kernel_launch(void* const* d_in, const int* in_sizes, int n_in,
                              void* d_out, int out_size, void* d_ws, size_t ws_size,
                              hipStream_t stream) {
    const float* C       = (const float*)d_in[0];
    const float* P       = (const float*)d_in[1];
    const float* theta_w = (const float*)d_in[2];
    const float* phi_w   = (const float*)d_in[3];
    const float* g_w     = (const float*)d_in[4];
    const float* out_w   = (const float*)d_in[5];
    float* out = (float*)d_out;

    ushort_t* ws = (ushort_t*)d_ws;
    ushort_t* thetaA = ws;                        // 8,388,608
    ushort_t* phiA   = ws + 8388608;              // 2,097,152
    ushort_t* gVx    = ws + 10485760;             // 2,097,152
    ushort_t* thWc   = ws + 12582912;             // 65,536
    ushort_t* phWc   = ws + 12648448;             // 65,536
    ushort_t* w2c    = ws + 12713984;             // 65,536

    prep_w<<<544, 256, 0, stream>>>(theta_w, phi_w, out_w, g_w, thWc, phWc, w2c);
    proj_all<<<768, 256, 0, stream>>>(thWc, phWc, w2c, C, P, thetaA, phiA, gVx);
    attn7<<<256, 512, 0, stream>>>(thetaA, phiA, gVx, C, out);
}